// Round 9
// baseline (282.994 us; speedup 1.0000x reference)
//
#include <hip/hip_runtime.h>
#include <stdint.h>

// Problem constants
#define Bz  4
#define Tz  2048
#define Ez  1024
#define Hz  16
#define HDz 64
#define Mz  (Bz*Tz)      // 8192 rows

typedef short bf16x8 __attribute__((ext_vector_type(8)));   // 8 bf16 in 4 VGPRs
typedef float f32x4  __attribute__((ext_vector_type(4)));
typedef unsigned short u16;

// fp32 -> bf16, round-half-up (differs from RNE only on exact ties, p~2^-16)
__device__ __forceinline__ u16 f2bf(float f) {
  return (u16)((__builtin_bit_cast(uint32_t, f) + 0x8000u) >> 16);
}
// pack two floats -> bf16x2 in one v_perm_b32: 3 VALU ops total (a -> low16, b -> high16)
__device__ __forceinline__ uint32_t pack2bf(float a, float b) {
  uint32_t ua = __builtin_bit_cast(uint32_t, a) + 0x8000u;
  uint32_t ub = __builtin_bit_cast(uint32_t, b) + 0x8000u;
  return __builtin_amdgcn_perm(ub, ua, 0x07060302u);  // [ua.hi16 | ub.hi16<<16]
}
// pack two floats -> bf16x2 in ONE instruction (RNE): D.lo=bf16(a), D.hi=bf16(b)
__device__ __forceinline__ uint32_t cvtpk2bf(float a, float b) {
  uint32_t r;
  asm("v_cvt_pk_bf16_f32 %0, %1, %2" : "=v"(r) : "v"(a), "v"(b));
  return r;
}

// raw v_exp_f32 (args are bounded; no denormal fixup needed)
#if __has_builtin(__builtin_amdgcn_exp2f)
#define EXP2(x) __builtin_amdgcn_exp2f(x)
#else
#define EXP2(x) exp2f(x)
#endif

// async global->LDS, 16B per lane; LDS dest is wave-uniform base + lane*16
__device__ __forceinline__ void gl2lds16(const u16* g, u16* l) {
  __builtin_amdgcn_global_load_lds((const __attribute__((address_space(1))) void*)g,
                                   (__attribute__((address_space(3))) void*)l, 16, 0, 0);
}

// ---------------- fused fp32 -> bf16 conversion (3 tensors, 1 launch) ----------------
__global__ void cvt_f32_bf16_3(const float* __restrict__ s0, u16* __restrict__ d0, int n0,
                               const float* __restrict__ s1, u16* __restrict__ d1, int n1,
                               const float* __restrict__ s2, u16* __restrict__ d2, int n2) {
  int j = blockIdx.x * blockDim.x + threadIdx.x;
  const float* s; u16* d;
  if (j < n0) { s = s0; d = d0; }
  else {
    j -= n0;
    if (j < n1) { s = s1; d = d1; }
    else { j -= n1; if (j >= n2) return; s = s2; d = d2; }
  }
  float4 f = ((const float4*)s)[j];
  uint2 o;
  o.x = pack2bf(f.x, f.y);
  o.y = pack2bf(f.z, f.w);
  ((uint2*)d)[j] = o;
}

// ---------------- GEMM: C[M,N] = A[M,K] * W[N,K]^T + bias ----------------
// R9: LDS-traffic-first restructure. R3/R4/R8 (64x64 or 64x32 wave tiles)
// all measured MfmaUtil ~25% regardless of sync structure or occupancy --
// because per-MFMA LDS operand traffic (1KB/N_rep + 1KB/M_rep = 512-768 B)
// exceeds the MFMA issue rate (budget ~620 B per 4.85-cyc MFMA at peak
// 128 B/cyc/CU; measured b128 rate is ~85 B/cyc). The GEMM was LDS-BW-bound.
// Fix: 128x64 wave tile (M_rep=8, N_rep=4) -> 384 B/MFMA -> MFMA becomes
// the longest pipe.
//   BM=256 BN=256 BK=64, 512 threads = 8 waves (2M x 4N),
//   acc[8][4] = 128 VGPR (~205 total; __launch_bounds__(512,2) caps at 256),
//   LDS 2 x 64 KB double-buffered = 128 KB -> 1 block/CU, 2 waves/SIMD.
// Sync skeleton = R3-proven: ONE __syncthreads per K-tile, prefetch issued
// AFTER the barrier. No setprio/sched_barrier (null in lockstep, m190).
// XOR-of-16B-chunk swizzle (involution, both sides) -> conflict-free
// ds_read_b128 (measured 0 conflicts in R0-R8).
// Grid: gemm0 12x32 = 384 blocks (1.5 rounds; quantization priced in),
//       gemm1 4x32 = 128 blocks.
// MODE 0: QKV epilogue; MODE 1: proj epilogue (fp32 out)
template<int MODE>
__global__ __launch_bounds__(512, 2) void gemm_bt(
    const u16* __restrict__ A, const u16* __restrict__ Bw,
    const float* __restrict__ bias,
    u16* __restrict__ qo, u16* __restrict__ ko, u16* __restrict__ vto,
    float* __restrict__ fo)
{
  __shared__ u16 Ab[2][256*64];   // 64 KB
  __shared__ u16 Bb[2][256*64];   // 64 KB
  const int tid  = threadIdx.x;
  const int lane = tid & 63;
  const int wid  = tid >> 6;          // 0..7
  const int quad = lane >> 4;
  const int cl   = lane & 15;
  const int wm   = wid >> 2;          // 0..1 (M): row offset wm*128
  const int wn   = wid & 3;           // 0..3 (N): col offset wn*64
  const int bm   = blockIdx.y * 256;
  const int bn   = blockIdx.x * 256;
  const int srow = lane >> 3;         // 0..7 row within 8-row staging chunk
  const int ssw  = lane & 7;          // linear chunk position in LDS

  f32x4 acc[8][4] = {};

  // 8 gl2lds16 per thread per K-tile: 4 for A (256 rows), 4 for B (256 rows)
  auto stage = [&](int kt, int buf) {
#pragma unroll
    for (int s = 0; s < 4; ++s) {
      const int r  = s*64 + wid*8 + srow;
      const int cc = ssw ^ (r & 7);
      gl2lds16(A + (size_t)(bm + r)*Ez + kt + cc*8, &Ab[buf][(s*64 + wid*8)*64]);
    }
#pragma unroll
    for (int s = 0; s < 4; ++s) {
      const int r  = s*64 + wid*8 + srow;
      const int cc = ssw ^ (r & 7);
      gl2lds16(Bw + (size_t)(bn + r)*Ez + kt + cc*8, &Bb[buf][(s*64 + wid*8)*64]);
    }
  };

  stage(0, 0);   // prologue: tile 0 into buffer 0

#pragma unroll 2
  for (int it = 0; it < 16; ++it) {
    const int bufc = it & 1;
    __syncthreads();                    // drains staging of tile it; buf^1 free
    if (it < 15) stage((it+1)*64, bufc^1);   // prefetch AFTER the barrier
    const u16* AB = &Ab[bufc][0];
    const u16* BB = &Bb[bufc][0];
#pragma unroll
    for (int ks = 0; ks < 2; ++ks) {
      bf16x8 af[8], bfr[4];
#pragma unroll
      for (int mi = 0; mi < 8; ++mi) {
        const int row = wm*128 + mi*16 + cl;
        const int ch  = (ks*4 + quad) ^ (row & 7);
        af[mi] = *(const bf16x8*)&AB[row*64 + ch*8];
      }
#pragma unroll
      for (int ni = 0; ni < 4; ++ni) {
        const int row = wn*64 + ni*16 + cl;
        const int ch  = (ks*4 + quad) ^ (row & 7);
        bfr[ni] = *(const bf16x8*)&BB[row*64 + ch*8];
      }
#pragma unroll
      for (int mi = 0; mi < 8; ++mi)
#pragma unroll
        for (int ni = 0; ni < 4; ++ni)
          acc[mi][ni] = __builtin_amdgcn_mfma_f32_16x16x32_bf16(af[mi], bfr[ni], acc[mi][ni], 0, 0, 0);
    }
  }

  const float qsc = 0.125f * 1.4426950408889634f;  // scale * log2(e), exp2 softmax domain
#pragma unroll
  for (int ni = 0; ni < 4; ++ni) {
    const int n   = bn + wn*64 + ni*16 + cl;
    const float bv = bias[n];
#pragma unroll
    for (int mi = 0; mi < 8; ++mi) {
      const int m0 = bm + wm*128 + mi*16 + quad*4;   // C row = quad*4 + reg
      if (MODE == 0) {
        const int which = n >> 10;        // 0=q 1=k 2=v (uniform: boundaries are multiples of 64)
        const int e = n & 1023;
        const int h = e >> 6, d = e & 63;
        const int b = m0 >> 11, t0 = m0 & 2047;
        if (which == 2) {
          // packed 8B store of 4 consecutive t
          uint2 pk;
          pk.x = pack2bf(acc[mi][ni][0] + bv, acc[mi][ni][1] + bv);
          pk.y = pack2bf(acc[mi][ni][2] + bv, acc[mi][ni][3] + bv);
          *(uint2*)&vto[(((size_t)(b*Hz + h))*HDz + d)*Tz + t0] = pk;
        } else {
#pragma unroll
          for (int r = 0; r < 4; ++r) {
            const int t = t0 + r;
            float val = acc[mi][ni][r] + bv;
            if (which == 0) qo[(((size_t)(b*Hz + h))*Tz + t)*HDz + d] = f2bf(val * qsc);
            else            ko[(((size_t)(b*Hz + h))*Tz + t)*HDz + d] = f2bf(val);
          }
        }
      } else {
#pragma unroll
        for (int r = 0; r < 4; ++r)
          fo[(size_t)(m0 + r)*Ez + n] = acc[mi][ni][r] + bv;
      }
    }
  }
}

// ---------------- Flash attention (S^T, no-max, 64-key staging, 32-key compute halves) ----------------
// R4-exact (best measured: 76.0 us). R5's 64q/wave halved occupancy and
// regressed; R6's zero-C + setprio-around-ST regressed (setprio starves
// co-resident waves' softmax VALU -- m190 lockstep-negative case). Reverted.
// grid = (B*H, T/128) bh-major. Block = 4 waves x 32 q-rows.
// Staging: 64-key K/V tiles, double-buffered, ONE __syncthreads per tile,
// prefetch issued after the barrier. Compute in two 32-key halves (keeps
// live score state at 16 VGPRs; R1's 64-key state spilled).
// No-max softmax (bounded scores, exp2 domain; Q pre-scaled by 0.125*log2e);
// row-sums l via ones-MFMA (C-layout, shfl-free epilogue).
// P redistribution (S^T C-layout -> PV A-fragment) in registers:
// v_cvt_pk_bf16_f32 then v_permlane32_swap + v_permlane16_swap
// (R1-R3 validated bit-exact). XOR-8 chunk swizzle on K and V (0 conflicts).
__global__ __launch_bounds__(256, 4) void attn_flash(
    const u16* __restrict__ Q, const u16* __restrict__ K,
    const u16* __restrict__ Vt, const unsigned char* __restrict__ mask,
    u16* __restrict__ ctx)
{
  __shared__ u16 Kb[2][64*64];     // 8 KB per buffer  [key][dim], XOR-8 swizzle
  __shared__ u16 Vb[2][64*64];     // 8 KB per buffer  [dim][key], XOR-8 swizzle

  const int tid  = threadIdx.x;
  const int lane = tid & 63;
  const int wid  = tid >> 6;
  const int quad = lane >> 4;
  const int cl   = lane & 15;
  const int bh   = blockIdx.x;        // b*16 + h
  const int b    = bh >> 4;
  const int qrw  = blockIdx.y * 128 + wid * 32;   // wave's 32-q-row base

  // staging lane mapping: 2 gl2lds per tensor per tile per thread, 8 rows each.
  // (row+8)&7 == row&7, so one swizzled chunk index serves both loads.
  const int srow = wid*16 + (lane >> 3);           // staging row (s=0)
  const int sch  = (lane & 7) ^ (srow & 7);        // swizzled 16B chunk (of 8)
  const u16* Kg = K  + ((size_t)bh*Tz + srow)*HDz + sch*8;   // + kt*HDz per tile
  const u16* Vg = Vt + ((size_t)bh*HDz + srow)*Tz + sch*8;   // + kt per tile
  u16* KbL[2] = { &Kb[0][(wid*16)*64], &Kb[1][(wid*16)*64] };
  u16* VbL[2] = { &Vb[0][(wid*16)*64], &Vb[1][(wid*16)*64] };

  auto stage = [&](int kt, int buf) {
    gl2lds16(Kg + (size_t)kt*HDz,           KbL[buf]);
    gl2lds16(Kg + (size_t)kt*HDz + 8*HDz,   KbL[buf] + 8*64);
    gl2lds16(Vg + kt,                       VbL[buf]);
    gl2lds16(Vg + kt + (size_t)8*Tz,        VbL[buf] + 8*64);
  };

  // mask pre-scan: 2048 bytes, 32 B/lane -> wave-uniform domask
  const unsigned char* mrow_p = mask + (size_t)b * Tz;
  bool domask;
  {
    const uint4* mp = (const uint4*)mrow_p;
    uint4 a = mp[lane*2], c = mp[lane*2 + 1];
    uint32_t any = a.x | a.y | a.z | a.w | c.x | c.y | c.z | c.w;
    domask = __any(any != 0);
  }

  // Q fragments for 2 q-sub-tiles (MFMA B-operand: lane n=cl -> qrow)
  bf16x8 aq[2][2];
#pragma unroll
  for (int qb = 0; qb < 2; ++qb) {
    const u16* Qg = Q + ((size_t)bh*Tz + qrw + qb*16 + cl)*HDz;
    aq[qb][0] = *(const bf16x8*)(Qg + quad*8);
    aq[qb][1] = *(const bf16x8*)(Qg + 32 + quad*8);
  }

  // ones B-fragment for l-accumulation MFMA (bf16 1.0 = 0x3F80)
  bf16x8 ones;
#pragma unroll
  for (int i = 0; i < 8; ++i) ones[i] = (short)0x3F80;

  f32x4 o[2][4] = {};       // [qb][db]: O rows quad*4+r, dims db*16+cl
  f32x4 lacc[2] = {};       // row-sums, C-layout rows quad*4+r

  stage(0, 0);              // prologue: tile 0 into buffer 0

#pragma unroll 2
  for (int it = 0; it < 32; ++it) {
    const int bufc = it & 1;
    __syncthreads();                  // drains this tile's staging; all waves done with buf^1
    if (it < 31) stage((it+1)*64, bufc^1);   // prefetch next tile AFTER the barrier
    const u16* KB = &Kb[bufc][0];
    const u16* VB = &Vb[bufc][0];
    const int kt = it * 64;

#pragma unroll
    for (int kv = 0; kv < 2; ++kv) {
      // S^T[key][qrow] for this 32-key half: A = K rows (lane m=cl -> key), B = Q frag
      f32x4 st[2][2] = {};
#pragma unroll
      for (int kb = 0; kb < 2; ++kb) {
        bf16x8 kf[2];
#pragma unroll
        for (int nb = 0; nb < 2; ++nb) {
          const int row = kv*32 + nb*16 + cl;          // key within tile
          const int ch  = (kb*4 + quad) ^ (row & 7);
          kf[nb] = *(const bf16x8*)&KB[row*64 + ch*8];
        }
#pragma unroll
        for (int qb = 0; qb < 2; ++qb)
#pragma unroll
          for (int nb = 0; nb < 2; ++nb)
            st[qb][nb] = __builtin_amdgcn_mfma_f32_16x16x32_bf16(kf[nb], aq[qb][kb], st[qb][nb], 0, 0, 0);
      }

      if (domask) {
#pragma unroll
        for (int nb = 0; nb < 2; ++nb) {
          uint32_t mm = *(const uint32_t*)&mrow_p[kt + kv*32 + nb*16 + quad*4];
          if (mm) {
#pragma unroll
            for (int qb = 0; qb < 2; ++qb) {
              if (mm & 0x000000ffu) st[qb][nb][0] = -INFINITY;
              if (mm & 0x0000ff00u) st[qb][nb][1] = -INFINITY;
              if (mm & 0x00ff0000u) st[qb][nb][2] = -INFINITY;
              if (mm & 0xff000000u) st[qb][nb][3] = -INFINITY;
            }
          }
        }
      }

      // P = exp2(S); in-register transpose to PV A-fragment via permlane swaps.
      // u* = nb=0 (keys kv*32 + 4q+{0..3}), v* = nb=1 (keys kv*32+16+4q+{0..3})
      bf16x8 pf[2];
#pragma unroll
      for (int qb = 0; qb < 2; ++qb) {
        uint32_t ux = cvtpk2bf(EXP2(st[qb][0][0]), EXP2(st[qb][0][1]));
        uint32_t uy = cvtpk2bf(EXP2(st[qb][0][2]), EXP2(st[qb][0][3]));
        uint32_t vx = cvtpk2bf(EXP2(st[qb][1][0]), EXP2(st[qb][1][1]));
        uint32_t vy = cvtpk2bf(EXP2(st[qb][1][2]), EXP2(st[qb][1][3]));
        asm("v_permlane32_swap_b32 %0, %1" : "+v"(ux), "+v"(vx));  // ux=[u.lo,v.lo] vx=[u.hi,v.hi]
        asm("v_permlane32_swap_b32 %0, %1" : "+v"(uy), "+v"(vy));
        asm("v_permlane16_swap_b32 %0, %1" : "+v"(ux), "+v"(vx));  // ux=keys 8q+{0,1} vx=keys 8q+{4,5}
        asm("v_permlane16_swap_b32 %0, %1" : "+v"(uy), "+v"(vy));  // uy=keys 8q+{2,3} vy=keys 8q+{6,7}
        int4 pi = { (int)ux, (int)uy, (int)vx, (int)vy };
        pf[qb] = __builtin_bit_cast(bf16x8, pi);
        lacc[qb] = __builtin_amdgcn_mfma_f32_16x16x32_bf16(pf[qb], ones, lacc[qb], 0, 0, 0);
      }

      // O += P*V for this half (K-dim = 32 keys); V-frags shared across qb
#pragma unroll
      for (int db = 0; db < 4; ++db) {
        const int row = db*16 + cl;                  // dim
        const int ch  = (kv*4 + quad) ^ (row & 7);
        bf16x8 bv = *(const bf16x8*)&VB[row*64 + ch*8];
#pragma unroll
        for (int qb = 0; qb < 2; ++qb)
          o[qb][db] = __builtin_amdgcn_mfma_f32_16x16x32_bf16(pf[qb], bv, o[qb][db], 0, 0, 0);
      }
    }
  }

  // epilogue: l already in C-layout (rows quad*4+r) — no shfls; coalesced stores
#pragma unroll
  for (int qb = 0; qb < 2; ++qb) {
#pragma unroll
    for (int r = 0; r < 4; ++r) {
      const float inv = 1.0f / lacc[qb][r];
      const int t = qrw + qb*16 + quad*4 + r;
      const size_t base = ((size_t)b*Tz + t)*Ez + (size_t)(bh & 15)*HDz;
#pragma unroll
      for (int db = 0; db < 4; ++db) {
        ctx[base + db*16 + cl] = f2bf(o[qb][db][r] * inv);
      }
    }
  }
}

// ---------------- launch ----------------
extern "C" void kernel_launch(void* const* d_in, const int* in_sizes, int n_in,
                              void* d_out, int out_size, void* d_ws, size_t ws_size,
                              hipStream_t stream) {
  (void)in_sizes; (void)n_in; (void)out_size; (void)ws_size;
  const float* x      = (const float*)d_in[0];
  const unsigned char* mask = (const unsigned char*)d_in[1];   // bool, 1B
  const float* qkv_w  = (const float*)d_in[2];
  const float* qkv_b  = (const float*)d_in[3];
  const float* proj_w = (const float*)d_in[4];
  const float* proj_b = (const float*)d_in[5];
  float* out = (float*)d_out;

  // workspace layout (bytes): total 92,274,688
  char* ws = (char*)d_ws;
  u16* xb   = (u16*)(ws + 0);          // x bf16            16 MB
  u16* wqb  = (u16*)(ws + 16777216);   // qkv_w bf16         6 MB
  u16* wpb  = (u16*)(ws + 23068672);   // proj_w bf16        2 MB
  u16* Qb   = (u16*)(ws + 25165824);   // Q [B,H,T,HD]      16 MB (pre-scaled)
  u16* Kb_  = (u16*)(ws + 41943040);   // K [B,H,T,HD]      16 MB
  u16* Vtb  = (u16*)(ws + 58720256);   // V^T [B,H,HD,T]    16 MB
  u16* ctxb = (u16*)(ws + 75497472);   // attn out [B,T,E]  16 MB

  // fused conversion: 2097152 + 786432 + 262144 = 3145728 float4 groups
  cvt_f32_bf16_3<<<12288, 256, 0, stream>>>(x, xb, 2097152,
                                            qkv_w, wqb, 786432,
                                            proj_w, wpb, 262144);

  gemm_bt<0><<<dim3(12, 32), 512, 0, stream>>>(xb, wqb, qkv_b, Qb, Kb_, Vtb, nullptr);
  attn_flash<<<dim3(64, 16), 256, 0, stream>>>(Qb, Kb_, Vtb, mask, ctxb);
  gemm_bt<1><<<dim3(4, 32), 512, 0, stream>>>(ctxb, wpb, proj_b, nullptr, nullptr, nullptr, out);
}

// Round 10
// 263.498 us; speedup vs baseline: 1.0740x; 1.0740x over previous
//
#include <hip/hip_runtime.h>
#include <stdint.h>

// Problem constants
#define Bz  4
#define Tz  2048
#define Ez  1024
#define Hz  16
#define HDz 64
#define Mz  (Bz*Tz)      // 8192 rows

typedef short bf16x8 __attribute__((ext_vector_type(8)));   // 8 bf16 in 4 VGPRs
typedef float f32x4  __attribute__((ext_vector_type(4)));
typedef unsigned short u16;

// fp32 -> bf16, round-half-up (differs from RNE only on exact ties, p~2^-16)
__device__ __forceinline__ u16 f2bf(float f) {
  return (u16)((__builtin_bit_cast(uint32_t, f) + 0x8000u) >> 16);
}
// pack two floats -> bf16x2 in one v_perm_b32: 3 VALU ops total (a -> low16, b -> high16)
__device__ __forceinline__ uint32_t pack2bf(float a, float b) {
  uint32_t ua = __builtin_bit_cast(uint32_t, a) + 0x8000u;
  uint32_t ub = __builtin_bit_cast(uint32_t, b) + 0x8000u;
  return __builtin_amdgcn_perm(ub, ua, 0x07060302u);  // [ua.hi16 | ub.hi16<<16]
}
// pack two floats -> bf16x2 in ONE instruction (RNE): D.lo=bf16(a), D.hi=bf16(b)
__device__ __forceinline__ uint32_t cvtpk2bf(float a, float b) {
  uint32_t r;
  asm("v_cvt_pk_bf16_f32 %0, %1, %2" : "=v"(r) : "v"(a), "v"(b));
  return r;
}

// raw v_exp_f32 (args are bounded; no denormal fixup needed)
#if __has_builtin(__builtin_amdgcn_exp2f)
#define EXP2(x) __builtin_amdgcn_exp2f(x)
#else
#define EXP2(x) exp2f(x)
#endif

// async global->LDS, 16B per lane; LDS dest is wave-uniform base + lane*16
__device__ __forceinline__ void gl2lds16(const u16* g, u16* l) {
  __builtin_amdgcn_global_load_lds((const __attribute__((address_space(1))) void*)g,
                                   (__attribute__((address_space(3))) void*)l, 16, 0, 0);
}

// ---------------- fused fp32 -> bf16 conversion (3 tensors, 1 launch) ----------------
__global__ void cvt_f32_bf16_3(const float* __restrict__ s0, u16* __restrict__ d0, int n0,
                               const float* __restrict__ s1, u16* __restrict__ d1, int n1,
                               const float* __restrict__ s2, u16* __restrict__ d2, int n2) {
  int j = blockIdx.x * blockDim.x + threadIdx.x;
  const float* s; u16* d;
  if (j < n0) { s = s0; d = d0; }
  else {
    j -= n0;
    if (j < n1) { s = s1; d = d1; }
    else { j -= n1; if (j >= n2) return; s = s2; d = d2; }
  }
  float4 f = ((const float4*)s)[j];
  uint2 o;
  o.x = pack2bf(f.x, f.y);
  o.y = pack2bf(f.z, f.w);
  ((uint2*)d)[j] = o;
}

// ---------------- GEMM: C[M,N] = A[M,K] * W[N,K]^T + bias ----------------
// R10: phase-interleaved counted-vmcnt structure (T3+T4+T5 together).
// Evidence: R3/R4/R8/R9 all ~25% MfmaUtil though pipe-balance caps are
// 38-62%; R4's counted-vmcnt-without-phases was null (catalog m196 V0) --
// the lever is the per-phase {ds_read || stage || MFMA} interleave WITH
// counted vmcnt (m201: 62% MfmaUtil).
//   BM=128 BN=256 BK=64, 512 threads = 8 waves (2M x 4N), wave 64x64,
//   acc[4][4] = 64 VGPR (spill-safe even at a 128-reg cap -- R9's lesson:
//   launch_bounds(512,2) on 8-wave blocks yielded a 128 cap + spill).
//   THREE LDS slots (3 x 48KB = 144KB), staging runs 2 K-tiles ahead,
//   6 loads/thread/K-tile (B:4, A:2) spread one pair per phase.
//   Per K-tile, 4 phases = (ks, mi-half), each:
//     {ds_read frags -> 2 x gl2lds -> s_barrier -> lgkmcnt(0)+sched_barrier
//      -> setprio(1) 8 MFMA setprio(0)}
//   Tile boundary: s_waitcnt vmcnt(6) (counted, never 0 until the tail:
//   exactly the 6 loads of tile t+2 stay in flight; tile t+1's are
//   guaranteed landed) + s_barrier. Each staged unit gets >=4 phases
//   (~1200 cyc) before first read -> HBM latency (~900) covered.
//   Race audit: every wave executes lgkmcnt(0) before its MFMAs, so all
//   ds_reads of slot s retire before the boundary barrier; the first
//   overwrite of s comes 2 tiles later, after that barrier.
// Grid: gemm0 12x64 = 768 blocks = 3 exact rounds @1 blk/CU;
//       gemm1  4x64 = 256 blocks = 1 exact round. No tail quantization.
// XOR-of-16B-chunk swizzle (involution, both sides) -> conflict-free
// ds_read_b128 (measured 0 conflicts R0-R9).
// MODE 0: QKV epilogue; MODE 1: proj epilogue (fp32 out)
template<int MODE>
__global__ __launch_bounds__(512, 2) void gemm_bt(
    const u16* __restrict__ A, const u16* __restrict__ Bw,
    const float* __restrict__ bias,
    u16* __restrict__ qo, u16* __restrict__ ko, u16* __restrict__ vto,
    float* __restrict__ fo)
{
  __shared__ u16 Lds[3][(128 + 256) * 64];   // 3 x 48 KB = 144 KB; A at 0, B at 128*64
  const int tid  = threadIdx.x;
  const int lane = tid & 63;
  const int wid  = tid >> 6;          // 0..7
  const int quad = lane >> 4;
  const int cl   = lane & 15;
  const int wm   = wid >> 2;          // 0..1 (M): rows wm*64
  const int wn   = wid & 3;           // 0..3 (N): cols wn*64
  const int bm   = blockIdx.y * 128;
  const int bn   = blockIdx.x * 256;

  // staging: each gl2lds issue covers 64 rows x 64 K (8 KB); thread ->
  // row = tid>>3 within issue, LDS chunk slot = tid&7, global chunk
  // cc = slot ^ (row&7) (XOR involution; (j*64+row)&7 == row&7).
  const int srow = tid >> 3;          // 0..63
  const int scc  = (tid & 7) ^ (srow & 7);
  const u16* Ag = A  + (size_t)(bm + srow)*Ez + scc*8;
  const u16* Bg = Bw + (size_t)(bn + srow)*Ez + scc*8;

  f32x4 acc[4][4] = {};

  auto stA = [&](int slot, int j, int kt) {
    gl2lds16(Ag + (size_t)(j*64)*Ez + kt, &Lds[slot][j*4096 + tid*8]);
  };
  auto stB = [&](int slot, int j, int kt) {
    gl2lds16(Bg + (size_t)(j*64)*Ez + kt, &Lds[slot][128*64 + j*4096 + tid*8]);
  };

  // prologue: tiles 0,1 in canonical per-tile order B0 B1 B2 B3 A0 A1
  stB(0,0,0);  stB(0,1,0);  stB(0,2,0);  stB(0,3,0);  stA(0,0,0);  stA(0,1,0);
  stB(1,0,64); stB(1,1,64); stB(1,2,64); stB(1,3,64); stA(1,0,64); stA(1,1,64);
  asm volatile("s_waitcnt vmcnt(6)" ::: "memory");   // tile 0 landed; tile 1 in flight
  __builtin_amdgcn_s_barrier();

  const int ch0 = quad ^ (cl & 7);         // ks=0 swizzled chunk
  const int ch1 = (4 + quad) ^ (cl & 7);   // ks=1 swizzled chunk

#pragma unroll
  for (int t = 0; t < 16; ++t) {
    const int slot = t % 3;
    const int s2   = (t + 2) % 3;
    const int kt2  = (t + 2) * 64;
    const bool st  = (t + 2) < 16;
    const u16* AB = &Lds[slot][0];
    const u16* BB = &Lds[slot][128*64];

    bf16x8 af[2], bfr[4];

    // ---- phase 0: ks0, mi 0-1, all ni ----
#pragma unroll
    for (int i = 0; i < 2; ++i)
      af[i] = *(const bf16x8*)&AB[(wm*64 + i*16 + cl)*64 + ch0*8];
#pragma unroll
    for (int n = 0; n < 4; ++n)
      bfr[n] = *(const bf16x8*)&BB[(wn*64 + n*16 + cl)*64 + ch0*8];
    if (st) { stB(s2,0,kt2); stB(s2,1,kt2); }
    __builtin_amdgcn_s_barrier();
    asm volatile("s_waitcnt lgkmcnt(0)" ::: "memory");
    __builtin_amdgcn_sched_barrier(0);
    __builtin_amdgcn_s_setprio(1);
#pragma unroll
    for (int i = 0; i < 2; ++i)
#pragma unroll
      for (int n = 0; n < 4; ++n)
        acc[i][n] = __builtin_amdgcn_mfma_f32_16x16x32_bf16(af[i], bfr[n], acc[i][n], 0, 0, 0);
    __builtin_amdgcn_s_setprio(0);

    // ---- phase 1: ks0, mi 2-3 ----
#pragma unroll
    for (int i = 0; i < 2; ++i)
      af[i] = *(const bf16x8*)&AB[(wm*64 + (2+i)*16 + cl)*64 + ch0*8];
    if (st) { stB(s2,2,kt2); stB(s2,3,kt2); }
    __builtin_amdgcn_s_barrier();
    asm volatile("s_waitcnt lgkmcnt(0)" ::: "memory");
    __builtin_amdgcn_sched_barrier(0);
    __builtin_amdgcn_s_setprio(1);
#pragma unroll
    for (int i = 0; i < 2; ++i)
#pragma unroll
      for (int n = 0; n < 4; ++n)
        acc[2+i][n] = __builtin_amdgcn_mfma_f32_16x16x32_bf16(af[i], bfr[n], acc[2+i][n], 0, 0, 0);
    __builtin_amdgcn_s_setprio(0);

    // ---- phase 2: ks1, mi 0-1 ----
#pragma unroll
    for (int i = 0; i < 2; ++i)
      af[i] = *(const bf16x8*)&AB[(wm*64 + i*16 + cl)*64 + ch1*8];
#pragma unroll
    for (int n = 0; n < 4; ++n)
      bfr[n] = *(const bf16x8*)&BB[(wn*64 + n*16 + cl)*64 + ch1*8];
    if (st) { stA(s2,0,kt2); stA(s2,1,kt2); }
    __builtin_amdgcn_s_barrier();
    asm volatile("s_waitcnt lgkmcnt(0)" ::: "memory");
    __builtin_amdgcn_sched_barrier(0);
    __builtin_amdgcn_s_setprio(1);
#pragma unroll
    for (int i = 0; i < 2; ++i)
#pragma unroll
      for (int n = 0; n < 4; ++n)
        acc[i][n] = __builtin_amdgcn_mfma_f32_16x16x32_bf16(af[i], bfr[n], acc[i][n], 0, 0, 0);
    __builtin_amdgcn_s_setprio(0);

    // ---- phase 3: ks1, mi 2-3 ----
#pragma unroll
    for (int i = 0; i < 2; ++i)
      af[i] = *(const bf16x8*)&AB[(wm*64 + (2+i)*16 + cl)*64 + ch1*8];
    __builtin_amdgcn_s_barrier();
    asm volatile("s_waitcnt lgkmcnt(0)" ::: "memory");
    __builtin_amdgcn_sched_barrier(0);
    __builtin_amdgcn_s_setprio(1);
#pragma unroll
    for (int i = 0; i < 2; ++i)
#pragma unroll
      for (int n = 0; n < 4; ++n)
        acc[2+i][n] = __builtin_amdgcn_mfma_f32_16x16x32_bf16(af[i], bfr[n], acc[2+i][n], 0, 0, 0);
    __builtin_amdgcn_s_setprio(0);

    // ---- tile boundary: counted drain (tile t+1 landed; t+2 in flight) ----
    if (t < 14)       asm volatile("s_waitcnt vmcnt(6)" ::: "memory");
    else if (t == 14) asm volatile("s_waitcnt vmcnt(0)" ::: "memory");
    if (t < 15) __builtin_amdgcn_s_barrier();
  }

  const float qsc = 0.125f * 1.4426950408889634f;  // scale * log2(e), exp2 softmax domain
#pragma unroll
  for (int ni = 0; ni < 4; ++ni) {
    const int n   = bn + wn*64 + ni*16 + cl;
    const float bv = bias[n];
#pragma unroll
    for (int mi = 0; mi < 4; ++mi) {
      const int m0 = bm + wm*64 + mi*16 + quad*4;   // C row = quad*4 + reg
      if (MODE == 0) {
        const int which = n >> 10;        // 0=q 1=k 2=v (uniform per block: 256 | 1024)
        const int e = n & 1023;
        const int h = e >> 6, d = e & 63;
        const int b = m0 >> 11, t0 = m0 & 2047;
        if (which == 2) {
          // packed 8B store of 4 consecutive t
          uint2 pk;
          pk.x = pack2bf(acc[mi][ni][0] + bv, acc[mi][ni][1] + bv);
          pk.y = pack2bf(acc[mi][ni][2] + bv, acc[mi][ni][3] + bv);
          *(uint2*)&vto[(((size_t)(b*Hz + h))*HDz + d)*Tz + t0] = pk;
        } else {
#pragma unroll
          for (int r = 0; r < 4; ++r) {
            const int t = t0 + r;
            float val = acc[mi][ni][r] + bv;
            if (which == 0) qo[(((size_t)(b*Hz + h))*Tz + t)*HDz + d] = f2bf(val * qsc);
            else            ko[(((size_t)(b*Hz + h))*Tz + t)*HDz + d] = f2bf(val);
          }
        }
      } else {
#pragma unroll
        for (int r = 0; r < 4; ++r)
          fo[(size_t)(m0 + r)*Ez + n] = acc[mi][ni][r] + bv;
      }
    }
  }
}

// ---------------- Flash attention (S^T, no-max, 64-key staging, 32-key compute halves) ----------------
// R4-exact (best measured: 76.0 us). R5's 64q/wave halved occupancy and
// regressed; R6's zero-C + setprio-around-ST regressed (setprio starves
// co-resident waves' softmax VALU -- m190 lockstep-negative case). Reverted.
// grid = (B*H, T/128) bh-major. Block = 4 waves x 32 q-rows.
// Staging: 64-key K/V tiles, double-buffered, ONE __syncthreads per tile,
// prefetch issued after the barrier. Compute in two 32-key halves (keeps
// live score state at 16 VGPRs; R1's 64-key state spilled).
// No-max softmax (bounded scores, exp2 domain; Q pre-scaled by 0.125*log2e);
// row-sums l via ones-MFMA (C-layout, shfl-free epilogue).
// P redistribution (S^T C-layout -> PV A-fragment) in registers:
// v_cvt_pk_bf16_f32 then v_permlane32_swap + v_permlane16_swap
// (R1-R3 validated bit-exact). XOR-8 chunk swizzle on K and V (0 conflicts).
__global__ __launch_bounds__(256, 4) void attn_flash(
    const u16* __restrict__ Q, const u16* __restrict__ K,
    const u16* __restrict__ Vt, const unsigned char* __restrict__ mask,
    u16* __restrict__ ctx)
{
  __shared__ u16 Kb[2][64*64];     // 8 KB per buffer  [key][dim], XOR-8 swizzle
  __shared__ u16 Vb[2][64*64];     // 8 KB per buffer  [dim][key], XOR-8 swizzle

  const int tid  = threadIdx.x;
  const int lane = tid & 63;
  const int wid  = tid >> 6;
  const int quad = lane >> 4;
  const int cl   = lane & 15;
  const int bh   = blockIdx.x;        // b*16 + h
  const int b    = bh >> 4;
  const int qrw  = blockIdx.y * 128 + wid * 32;   // wave's 32-q-row base

  // staging lane mapping: 2 gl2lds per tensor per tile per thread, 8 rows each.
  // (row+8)&7 == row&7, so one swizzled chunk index serves both loads.
  const int srow = wid*16 + (lane >> 3);           // staging row (s=0)
  const int sch  = (lane & 7) ^ (srow & 7);        // swizzled 16B chunk (of 8)
  const u16* Kg = K  + ((size_t)bh*Tz + srow)*HDz + sch*8;   // + kt*HDz per tile
  const u16* Vg = Vt + ((size_t)bh*HDz + srow)*Tz + sch*8;   // + kt per tile
  u16* KbL[2] = { &Kb[0][(wid*16)*64], &Kb[1][(wid*16)*64] };
  u16* VbL[2] = { &Vb[0][(wid*16)*64], &Vb[1][(wid*16)*64] };

  auto stage = [&](int kt, int buf) {
    gl2lds16(Kg + (size_t)kt*HDz,           KbL[buf]);
    gl2lds16(Kg + (size_t)kt*HDz + 8*HDz,   KbL[buf] + 8*64);
    gl2lds16(Vg + kt,                       VbL[buf]);
    gl2lds16(Vg + kt + (size_t)8*Tz,        VbL[buf] + 8*64);
  };

  // mask pre-scan: 2048 bytes, 32 B/lane -> wave-uniform domask
  const unsigned char* mrow_p = mask + (size_t)b * Tz;
  bool domask;
  {
    const uint4* mp = (const uint4*)mrow_p;
    uint4 a = mp[lane*2], c = mp[lane*2 + 1];
    uint32_t any = a.x | a.y | a.z | a.w | c.x | c.y | c.z | c.w;
    domask = __any(any != 0);
  }

  // Q fragments for 2 q-sub-tiles (MFMA B-operand: lane n=cl -> qrow)
  bf16x8 aq[2][2];
#pragma unroll
  for (int qb = 0; qb < 2; ++qb) {
    const u16* Qg = Q + ((size_t)bh*Tz + qrw + qb*16 + cl)*HDz;
    aq[qb][0] = *(const bf16x8*)(Qg + quad*8);
    aq[qb][1] = *(const bf16x8*)(Qg + 32 + quad*8);
  }

  // ones B-fragment for l-accumulation MFMA (bf16 1.0 = 0x3F80)
  bf16x8 ones;
#pragma unroll
  for (int i = 0; i < 8; ++i) ones[i] = (short)0x3F80;

  f32x4 o[2][4] = {};       // [qb][db]: O rows quad*4+r, dims db*16+cl
  f32x4 lacc[2] = {};       // row-sums, C-layout rows quad*4+r

  stage(0, 0);              // prologue: tile 0 into buffer 0

#pragma unroll 2
  for (int it = 0; it < 32; ++it) {
    const int bufc = it & 1;
    __syncthreads();                  // drains this tile's staging; all waves done with buf^1
    if (it < 31) stage((it+1)*64, bufc^1);   // prefetch next tile AFTER the barrier
    const u16* KB = &Kb[bufc][0];
    const u16* VB = &Vb[bufc][0];
    const int kt = it * 64;

#pragma unroll
    for (int kv = 0; kv < 2; ++kv) {
      // S^T[key][qrow] for this 32-key half: A = K rows (lane m=cl -> key), B = Q frag
      f32x4 st[2][2] = {};
#pragma unroll
      for (int kb = 0; kb < 2; ++kb) {
        bf16x8 kf[2];
#pragma unroll
        for (int nb = 0; nb < 2; ++nb) {
          const int row = kv*32 + nb*16 + cl;          // key within tile
          const int ch  = (kb*4 + quad) ^ (row & 7);
          kf[nb] = *(const bf16x8*)&KB[row*64 + ch*8];
        }
#pragma unroll
        for (int qb = 0; qb < 2; ++qb)
#pragma unroll
          for (int nb = 0; nb < 2; ++nb)
            st[qb][nb] = __builtin_amdgcn_mfma_f32_16x16x32_bf16(kf[nb], aq[qb][kb], st[qb][nb], 0, 0, 0);
      }

      if (domask) {
#pragma unroll
        for (int nb = 0; nb < 2; ++nb) {
          uint32_t mm = *(const uint32_t*)&mrow_p[kt + kv*32 + nb*16 + quad*4];
          if (mm) {
#pragma unroll
            for (int qb = 0; qb < 2; ++qb) {
              if (mm & 0x000000ffu) st[qb][nb][0] = -INFINITY;
              if (mm & 0x0000ff00u) st[qb][nb][1] = -INFINITY;
              if (mm & 0x00ff0000u) st[qb][nb][2] = -INFINITY;
              if (mm & 0xff000000u) st[qb][nb][3] = -INFINITY;
            }
          }
        }
      }

      // P = exp2(S); in-register transpose to PV A-fragment via permlane swaps.
      // u* = nb=0 (keys kv*32 + 4q+{0..3}), v* = nb=1 (keys kv*32+16+4q+{0..3})
      bf16x8 pf[2];
#pragma unroll
      for (int qb = 0; qb < 2; ++qb) {
        uint32_t ux = cvtpk2bf(EXP2(st[qb][0][0]), EXP2(st[qb][0][1]));
        uint32_t uy = cvtpk2bf(EXP2(st[qb][0][2]), EXP2(st[qb][0][3]));
        uint32_t vx = cvtpk2bf(EXP2(st[qb][1][0]), EXP2(st[qb][1][1]));
        uint32_t vy = cvtpk2bf(EXP2(st[qb][1][2]), EXP2(st[qb][1][3]));
        asm("v_permlane32_swap_b32 %0, %1" : "+v"(ux), "+v"(vx));  // ux=[u.lo,v.lo] vx=[u.hi,v.hi]
        asm("v_permlane32_swap_b32 %0, %1" : "+v"(uy), "+v"(vy));
        asm("v_permlane16_swap_b32 %0, %1" : "+v"(ux), "+v"(vx));  // ux=keys 8q+{0,1} vx=keys 8q+{4,5}
        asm("v_permlane16_swap_b32 %0, %1" : "+v"(uy), "+v"(vy));  // uy=keys 8q+{2,3} vy=keys 8q+{6,7}
        int4 pi = { (int)ux, (int)uy, (int)vx, (int)vy };
        pf[qb] = __builtin_bit_cast(bf16x8, pi);
        lacc[qb] = __builtin_amdgcn_mfma_f32_16x16x32_bf16(pf[qb], ones, lacc[qb], 0, 0, 0);
      }

      // O += P*V for this half (K-dim = 32 keys); V-frags shared across qb
#pragma unroll
      for (int db = 0; db < 4; ++db) {
        const int row = db*16 + cl;                  // dim
        const int ch  = (kv*4 + quad) ^ (row & 7);
        bf16x8 bv = *(const bf16x8*)&VB[row*64 + ch*8];
#pragma unroll
        for (int qb = 0; qb < 2; ++qb)
          o[qb][db] = __builtin_amdgcn_mfma_f32_16x16x32_bf16(pf[qb], bv, o[qb][db], 0, 0, 0);
      }
    }
  }

  // epilogue: l already in C-layout (rows quad*4+r) — no shfls; coalesced stores
#pragma unroll
  for (int qb = 0; qb < 2; ++qb) {
#pragma unroll
    for (int r = 0; r < 4; ++r) {
      const float inv = 1.0f / lacc[qb][r];
      const int t = qrw + qb*16 + quad*4 + r;
      const size_t base = ((size_t)b*Tz + t)*Ez + (size_t)(bh & 15)*HDz;
#pragma unroll
      for (int db = 0; db < 4; ++db) {
        ctx[base + db*16 + cl] = f2bf(o[qb][db][r] * inv);
      }
    }
  }
}

// ---------------- launch ----------------
extern "C" void kernel_launch(void* const* d_in, const int* in_sizes, int n_in,
                              void* d_out, int out_size, void* d_ws, size_t ws_size,
                              hipStream_t stream) {
  (void)in_sizes; (void)n_in; (void)out_size; (void)ws_size;
  const float* x      = (const float*)d_in[0];
  const unsigned char* mask = (const unsigned char*)d_in[1];   // bool, 1B
  const float* qkv_w  = (const float*)d_in[2];
  const float* qkv_b  = (const float*)d_in[3];
  const float* proj_w = (const float*)d_in[4];
  const float* proj_b = (const float*)d_in[5];
  float* out = (float*)d_out;

  // workspace layout (bytes): total 92,274,688
  char* ws = (char*)d_ws;
  u16* xb   = (u16*)(ws + 0);          // x bf16            16 MB
  u16* wqb  = (u16*)(ws + 16777216);   // qkv_w bf16         6 MB
  u16* wpb  = (u16*)(ws + 23068672);   // proj_w bf16        2 MB
  u16* Qb   = (u16*)(ws + 25165824);   // Q [B,H,T,HD]      16 MB (pre-scaled)
  u16* Kb_  = (u16*)(ws + 41943040);   // K [B,H,T,HD]      16 MB
  u16* Vtb  = (u16*)(ws + 58720256);   // V^T [B,H,HD,T]    16 MB
  u16* ctxb = (u16*)(ws + 75497472);   // attn out [B,T,E]  16 MB

  // fused conversion: 2097152 + 786432 + 262144 = 3145728 float4 groups
  cvt_f32_bf16_3<<<12288, 256, 0, stream>>>(x, xb, 2097152,
                                            qkv_w, wqb, 786432,
                                            proj_w, wpb, 262144);

  gemm_bt<0><<<dim3(12, 64), 512, 0, stream>>>(xb, wqb, qkv_b, Qb, Kb_, Vtb, nullptr);
  attn_flash<<<dim3(64, 16), 256, 0, stream>>>(Qb, Kb_, Vtb, mask, ctxb);
  gemm_bt<1><<<dim3(4, 64), 512, 0, stream>>>(ctxb, wpb, proj_b, nullptr, nullptr, nullptr, out);
}